// Round 5
// baseline (4996.550 us; speedup 1.0000x reference)
//
#include <hip/hip_runtime.h>

#define L_SEQ 512
#define NB    64
#define DDIM  512
#define HHALF 256
#define GG    1024   // 4*HALF

using f32x4  = __attribute__((ext_vector_type(4))) float;
using bf16x8 = __attribute__((ext_vector_type(8))) short;
using half4  = __attribute__((ext_vector_type(4))) _Float16;
typedef unsigned int u32;

__device__ __forceinline__ unsigned short f2bf(float f) {
    unsigned u = __float_as_uint(f);
    u += 0x7fffu + ((u >> 16) & 1u);          // round-to-nearest-even
    return (unsigned short)(u >> 16);
}
__device__ __forceinline__ float fsigmoid(float x) {
    return 1.0f / (1.0f + __expf(-x));
}
__device__ __forceinline__ float ftanh(float x) {
    return 1.0f - 2.0f / (__expf(2.0f * x) + 1.0f);
}

// ---------------------------------------------------------------------------
// Phase 1: xwb[dir][t][b][g] (fp16) = x[t][b][:] . W_ih[g][:] + b_ih[g] + b_hh[g]
// fp32 GEMM, M=32768, N=1024, K=512. Tile 128x128x8, 8x8/thread. Unchanged
// (proven). Block (0,0,0) zero-inits Hbuf + flags.
// ---------------------------------------------------------------------------
__global__ __launch_bounds__(256) void gemm_xwb(
    const float* __restrict__ x,
    const float* __restrict__ Wf, const float* __restrict__ Wb,
    const float* __restrict__ bihf, const float* __restrict__ bhhf,
    const float* __restrict__ bihb, const float* __restrict__ bhhb,
    _Float16* __restrict__ xwb,
    unsigned int* __restrict__ zero_base, int zero_words)
{
    const int dir = blockIdx.z;
    const float* __restrict__ W   = dir ? Wb   : Wf;
    const float* __restrict__ bih = dir ? bihb : bihf;
    const float* __restrict__ bhh = dir ? bhhb : bhhf;
    const int n0 = blockIdx.x * 128;
    const int m0 = blockIdx.y * 128;

    if (blockIdx.x == 0 && blockIdx.y == 0 && blockIdx.z == 0) {
        for (int i = threadIdx.x; i < zero_words; i += 256)
            zero_base[i] = 0u;
    }

    __shared__ float As[8][128];
    __shared__ float Ws[8][128];

    const int t   = threadIdx.x;
    const int row = t >> 1;
    const int kq  = (t & 1) * 4;
    const int tm  = t >> 4;
    const int tn  = t & 15;

    float acc[8][8];
#pragma unroll
    for (int i = 0; i < 8; ++i)
#pragma unroll
        for (int jj = 0; jj < 8; ++jj) acc[i][jj] = 0.f;

    const float* xa = x + (size_t)(m0 + row) * DDIM + kq;
    const float* wa = W + (size_t)(n0 + row) * DDIM + kq;

    for (int k0 = 0; k0 < DDIM; k0 += 8) {
        float4 av = *(const float4*)(xa + k0);
        float4 wv = *(const float4*)(wa + k0);
        __syncthreads();
        As[kq + 0][row] = av.x; As[kq + 1][row] = av.y;
        As[kq + 2][row] = av.z; As[kq + 3][row] = av.w;
        Ws[kq + 0][row] = wv.x; Ws[kq + 1][row] = wv.y;
        Ws[kq + 2][row] = wv.z; Ws[kq + 3][row] = wv.w;
        __syncthreads();
#pragma unroll
        for (int k = 0; k < 8; ++k) {
            float4 a0 = *(const float4*)&As[k][tm * 4];
            float4 a1 = *(const float4*)&As[k][64 + tm * 4];
            float4 b0 = *(const float4*)&Ws[k][tn * 4];
            float4 b1 = *(const float4*)&Ws[k][64 + tn * 4];
            float aa[8] = {a0.x, a0.y, a0.z, a0.w, a1.x, a1.y, a1.z, a1.w};
            float bb[8] = {b0.x, b0.y, b0.z, b0.w, b1.x, b1.y, b1.z, b1.w};
#pragma unroll
            for (int i = 0; i < 8; ++i)
#pragma unroll
                for (int jj = 0; jj < 8; ++jj)
                    acc[i][jj] = __builtin_fmaf(aa[i], bb[jj], acc[i][jj]);
        }
    }

    float bias[8];
#pragma unroll
    for (int jj = 0; jj < 8; ++jj) {
        int col = n0 + ((jj < 4) ? (tn * 4 + jj) : (64 + tn * 4 + jj - 4));
        bias[jj] = bih[col] + bhh[col];
    }
#pragma unroll
    for (int i = 0; i < 8; ++i) {
        int m = m0 + ((i < 4) ? (tm * 4 + i) : (64 + tm * 4 + i - 4));
        _Float16* op = xwb + ((size_t)dir * (L_SEQ * NB) + m) * GG + n0;
        half4 v0, v1;
#pragma unroll
        for (int jj = 0; jj < 4; ++jj) v0[jj] = (_Float16)(acc[i][jj] + bias[jj]);
#pragma unroll
        for (int jj = 0; jj < 4; ++jj) v1[jj] = (_Float16)(acc[i][4 + jj] + bias[4 + jj]);
        *(half4*)(op + tn * 4) = v0;
        *(half4*)(op + 64 + tn * 4) = v1;
    }
}

// ---------------------------------------------------------------------------
// Phase 2 (v4): R2's PROVEN acquire/release protocol, restructured to cut
// fence payload and domain count:
//  - 16 blocks x 512 thr (8 waves). Group = (dir, batch-16) = 2 blocks
//    (128 h-cols each) -> half the inv/wbl2 sites of R2's 4-block groups.
//  - Protocol per step (verbatim R2 semantics): tid0 acquire-spin ->
//    __syncthreads -> compute -> h stores (plain, u32-packed) ->
//    __threadfence -> __syncthreads -> tid0 release-add.
//  - fp32 out stores are NONTEMPORAL and issued AFTER the release-add:
//    off the fence's wbl2/vmcnt path (they drain during next step's wait).
// ---------------------------------------------------------------------------
__global__ __launch_bounds__(512, 2) void lstm_recur(
    const _Float16* __restrict__ xwb,
    const float* __restrict__ Whh_f,
    const float* __restrict__ Whh_b,
    const float* __restrict__ mask,
    float* __restrict__ out,
    unsigned short* __restrict__ Hbuf,    // [phase][dir][64][256] bf16
    unsigned int* __restrict__ flags)     // [8] stride 32 uints
{
    const int bid = blockIdx.x;           // 0..15
    const int grp = bid & 7;              // dir*4 + gb
    const int dir = grp >> 2;
    const int gb  = grp & 3;
    const int g2  = bid >> 3;             // h-col half: 0 or 1 (128 cols)
    unsigned int* cnt = flags + grp * 32;

    const int tid = threadIdx.x;
    const int w   = tid >> 6;             // wave 0..7
    const int l   = tid & 63;
    const int q   = l >> 4;
    const int c   = l & 15;

    const int b0 = gb * 16;               // group's batch base
    const int j  = 128 * g2 + 16 * w + c; // h column [0,256)

    // --- B fragments: W_hh slice, register resident ---
    // gate t: B[k][n=c] = W_hh[t*256 + j][k], lane k-range kt*32+q*8..+7
    const float* __restrict__ Whh = dir ? Whh_b : Whh_f;
    bf16x8 bfrag[4][8];
#pragma unroll
    for (int t = 0; t < 4; ++t) {
        const int gcol = t * HHALF + j;
#pragma unroll
        for (int kt = 0; kt < 8; ++kt) {
            const float4* wp = (const float4*)(Whh + (size_t)gcol * HHALF + kt * 32 + q * 8);
            float4 w0 = wp[0], w1 = wp[1];
            bf16x8 v;
            v[0] = (short)f2bf(w0.x); v[1] = (short)f2bf(w0.y);
            v[2] = (short)f2bf(w0.z); v[3] = (short)f2bf(w0.w);
            v[4] = (short)f2bf(w1.x); v[5] = (short)f2bf(w1.y);
            v[6] = (short)f2bf(w1.z); v[7] = (short)f2bf(w1.w);
            bfrag[t][kt] = v;
        }
    }

    float cstate[4] = {0.f, 0.f, 0.f, 0.f};

    for (int step = 0; step < L_SEQ; ++step) {
        const int tt = dir ? (L_SEQ - 1 - step) : step;

        // ---- prefetch (independent of h): xwb + mask for this step ----
        float xv[4][4];
        const _Float16* xp = xwb + ((size_t)(dir * L_SEQ + tt) * NB + b0 + q * 4) * GG + j;
#pragma unroll
        for (int t = 0; t < 4; ++t)
#pragma unroll
            for (int r = 0; r < 4; ++r)
                xv[t][r] = (float)xp[(size_t)r * GG + t * HHALF];
        float mv[4];
#pragma unroll
        for (int r = 0; r < 4; ++r) mv[r] = mask[tt * NB + b0 + q * 4 + r];

        // ---- wait for the group's 2 blocks to have published step-1 ----
        if (tid == 0) {
            const unsigned target = 2u * (unsigned)step;
            while (__hip_atomic_load(cnt, __ATOMIC_ACQUIRE, __HIP_MEMORY_SCOPE_AGENT) < target) {}
        }
        __syncthreads();

        const unsigned short* __restrict__ Hr =
            Hbuf + (size_t)((step & 1) * 2 + dir) * NB * HHALF;
        unsigned short* __restrict__ Hw =
            Hbuf + (size_t)(((step + 1) & 1) * 2 + dir) * NB * HHALF;

        // ---- A fragments: h rows b0..b0+15, full K=256 ----
        bf16x8 afrag[8];
        const unsigned short* hp = Hr + (size_t)(b0 + c) * HHALF;
#pragma unroll
        for (int kt = 0; kt < 8; ++kt)
            afrag[kt] = *(const bf16x8*)(hp + kt * 32 + q * 8);

        // ---- gates = xW (+biases) + h @ W_hh^T ----
        f32x4 acc[4];
#pragma unroll
        for (int t = 0; t < 4; ++t) {
            f32x4 a; a[0] = xv[t][0]; a[1] = xv[t][1]; a[2] = xv[t][2]; a[3] = xv[t][3];
            acc[t] = a;
        }
#pragma unroll
        for (int kt = 0; kt < 8; ++kt)
#pragma unroll
            for (int t = 0; t < 4; ++t)
                acc[t] = __builtin_amdgcn_mfma_f32_16x16x32_bf16(afrag[kt], bfrag[t][kt], acc[t], 0, 0, 0);

        // ---- elementwise: lane holds i,f,g,o for (b0+q*4+r, j) ----
        float hval[4];
#pragma unroll
        for (int r = 0; r < 4; ++r) {
            float gi = acc[0][r], gf = acc[1][r], gg = acc[2][r], go = acc[3][r];
            float cn = fsigmoid(gf) * cstate[r] + fsigmoid(gi) * ftanh(gg);
            float h  = fsigmoid(go) * ftanh(cn);
            float m  = mv[r];
            h  *= m;
            cn *= m;
            cstate[r] = cn;
            hval[r] = h;
        }

        // ---- publish h: pack lane-pairs to u32, plain stores ----
#pragma unroll
        for (int r = 0; r < 4; ++r) {
            unsigned mine  = (unsigned)f2bf(hval[r]);
            unsigned other = __shfl_xor(mine, 1);     // partner col j^1
            if ((c & 1) == 0) {
                unsigned word = mine | (other << 16);
                *(u32*)(Hw + (size_t)(b0 + q * 4 + r) * HHALF + j) = word;
            }
        }

        // ---- R2-proven release sequence ----
        __threadfence();
        __syncthreads();
        if (tid == 0)
            __hip_atomic_fetch_add(cnt, 1u, __ATOMIC_RELEASE, __HIP_MEMORY_SCOPE_AGENT);

        // ---- fp32 output: nontemporal, off the fence path ----
#pragma unroll
        for (int r = 0; r < 4; ++r) {
            const int b = b0 + q * 4 + r;
            __builtin_nontemporal_store(hval[r],
                &out[((size_t)tt * NB + b) * (2 * HHALF) + dir * HHALF + j]);
        }
    }
}

// ---------------------------------------------------------------------------
// Workspace layout:
//   [0, 128 MiB)            xwb   fp16 [2][512][64][1024]
//   [+0,   +128 KiB)        Hbuf  bf16 [2 phases][2 dirs][64][256]
//   [+128K, +1 KiB)         flags u32 [8] stride 32
// Requires ws_size >= 134,349,824 bytes.
// ---------------------------------------------------------------------------
extern "C" void kernel_launch(void* const* d_in, const int* in_sizes, int n_in,
                              void* d_out, int out_size, void* d_ws, size_t ws_size,
                              hipStream_t stream)
{
    (void)in_sizes; (void)n_in; (void)out_size; (void)ws_size;
    const float* x     = (const float*)d_in[0];
    const float* mask  = (const float*)d_in[1];
    const float* Wih_f = (const float*)d_in[2];
    const float* Whh_f = (const float*)d_in[3];
    const float* bih_f = (const float*)d_in[4];
    const float* bhh_f = (const float*)d_in[5];
    const float* Wih_b = (const float*)d_in[6];
    const float* Whh_b = (const float*)d_in[7];
    const float* bih_b = (const float*)d_in[8];
    const float* bhh_b = (const float*)d_in[9];
    float* out = (float*)d_out;

    const size_t xwb_bytes  = (size_t)2 * L_SEQ * NB * GG * sizeof(_Float16);
    const size_t hbuf_bytes = (size_t)2 * 2 * NB * HHALF * sizeof(unsigned short);
    _Float16*       xwb   = (_Float16*)d_ws;
    unsigned short* Hbuf  = (unsigned short*)((char*)d_ws + xwb_bytes);
    unsigned int*   flags = (unsigned int*)((char*)d_ws + xwb_bytes + hbuf_bytes);

    // gemm_xwb also zero-inits Hbuf + flags (33,024 words) from block (0,0,0)
    const int zero_words = (int)((hbuf_bytes + 8 * 32 * sizeof(unsigned int)) / 4);
    hipLaunchKernelGGL(gemm_xwb, dim3(8, 256, 2), dim3(256), 0, stream,
                       x, Wih_f, Wih_b, bih_f, bhh_f, bih_b, bhh_b, xwb,
                       (unsigned int*)Hbuf, zero_words);

    hipLaunchKernelGGL(lstm_recur, dim3(16), dim3(512), 0, stream,
                       xwb, Whh_f, Whh_b, mask, out, Hbuf, flags);
}